// Round 6
// baseline (472.237 us; speedup 1.0000x reference)
//
#include <hip/hip_runtime.h>
#include <math.h>

#define N_NODES 50000
#define N_EDGES 800000
#define HID 256
#define OUT_C 128
#define NEG_SLOPE 0.2f
#define SCAN_NB ((N_NODES + 255) / 256)   // 196

typedef __attribute__((ext_vector_type(8))) short bf16x8;   // 8 bf16 (4 VGPRs)
typedef __attribute__((ext_vector_type(4))) float f32x4;    // MFMA C/D

__device__ inline unsigned short bf16_rne(float x) {
    unsigned u = __float_as_uint(x);
    return (unsigned short)((u + 0x7fffu + ((u >> 16) & 1u)) >> 16);
}

// ---------------- CSR build (per call; int atomics only) ----------------

__global__ __launch_bounds__(256) void hist_kernel(
    const int* __restrict__ dst, int* __restrict__ counts) {
    int e = blockIdx.x * 256 + threadIdx.x;
    if (e < N_EDGES) atomicAdd(&counts[dst[e]], 1);
}

__global__ __launch_bounds__(256) void block_scan_kernel(
    const int* __restrict__ counts, int* __restrict__ excl,
    int* __restrict__ blockSums, int n) {
    __shared__ int waveSums[4];
    int i = blockIdx.x * 256 + threadIdx.x;
    int lane = threadIdx.x & 63;
    int wv = threadIdx.x >> 6;
    int c = (i < n) ? counts[i] : 0;
    int v = c;
    #pragma unroll
    for (int off = 1; off < 64; off <<= 1) {
        int t = __shfl_up(v, off);
        if (lane >= off) v += t;
    }
    if (lane == 63) waveSums[wv] = v;
    __syncthreads();
    int waveOff = 0;
    #pragma unroll
    for (int w = 0; w < 4; w++)
        if (w < wv) waveOff += waveSums[w];
    if (i < n) excl[i] = waveOff + v - c;
    if (threadIdx.x == 255) blockSums[blockIdx.x] = waveOff + v;
}

__global__ __launch_bounds__(64) void scan_sums_kernel(
    int* __restrict__ blockSums, int nb) {
    int lane = threadIdx.x;
    int run = 0;
    for (int base = 0; base < nb; base += 64) {
        int i = base + lane;
        int c = (i < nb) ? blockSums[i] : 0;
        int v = c;
        #pragma unroll
        for (int off = 1; off < 64; off <<= 1) {
            int t = __shfl_up(v, off);
            if (lane >= off) v += t;
        }
        if (i < nb) blockSums[i] = run + v - c;
        run += __shfl(v, 63);
    }
}

// also zeroes cursor (the counts array, free after block_scan)
__global__ __launch_bounds__(256) void add_offsets_kernel(
    int* __restrict__ excl, const int* __restrict__ blockSums,
    int* __restrict__ cursor, int n) {
    int i = blockIdx.x * 256 + threadIdx.x;
    if (i < n) {
        excl[i] += blockSums[blockIdx.x];
        cursor[i] = 0;
    }
    if (i == 0) excl[n] = N_EDGES;
}

__global__ __launch_bounds__(256) void scatter_kernel(
    const int* __restrict__ src, const int* __restrict__ dst,
    const int* __restrict__ offsets, int* __restrict__ cursor,
    int* __restrict__ src_sorted) {
    int e = blockIdx.x * 256 + threadIdx.x;
    if (e >= N_EDGES) return;
    int d = dst[e];
    int pos = offsets[d] + atomicAdd(&cursor[d], 1);
    src_sorted[pos] = src[e];
}

// ---------------- v = W @ att for all 4 (layer,side) combos ----------------

__global__ __launch_bounds__(64) void compute_v_all_kernel(
    const float* __restrict__ W1s, const float* __restrict__ att1s,
    const float* __restrict__ W1d, const float* __restrict__ att1d,
    const float* __restrict__ W2s, const float* __restrict__ att2s,
    const float* __restrict__ W2d, const float* __restrict__ att2d,
    float* __restrict__ v1s, float* __restrict__ v1d,
    float* __restrict__ v2s, float* __restrict__ v2d) {
    int k = blockIdx.x;
    int lane = threadIdx.x;
    const float* W; const float* att; float* v; int cout;
    switch (blockIdx.y) {
        case 0: W = W1s; att = att1s; v = v1s; cout = HID; break;
        case 1: W = W1d; att = att1d; v = v1d; cout = HID; break;
        case 2: W = W2s; att = att2s; v = v2s; cout = OUT_C; break;
        default: W = W2d; att = att2d; v = v2d; cout = OUT_C; break;
    }
    float sum = 0.f;
    for (int j = lane; j < cout; j += 64)
        sum += W[k * cout + j] * att[j];
    #pragma unroll
    for (int off = 32; off > 0; off >>= 1)
        sum += __shfl_down(sum, off);
    if (lane == 0) v[k] = sum;
}

// ---------------- pack W (+v tile) into B-fragment layout, hi/lo bf16, both layers ----
// layer buffer: frag index = (ks*NT + tile)*64 + lane, 8 elems each.
// tile < NT-1: B[k][tile*16+m]; tile == NT-1: col0=v_s[k], col1=v_d[k], else 0.

#define PACK1_T (8 * 17 * 64)   // 8704
#define PACK2_T (8 * 9 * 64)    // 4608

__global__ __launch_bounds__(256) void pack_all_kernel(
    const float* __restrict__ W1, const float* __restrict__ v1s, const float* __restrict__ v1d,
    const float* __restrict__ W2, const float* __restrict__ v2s, const float* __restrict__ v2d,
    unsigned short* __restrict__ hi1, unsigned short* __restrict__ lo1,
    unsigned short* __restrict__ hi2, unsigned short* __restrict__ lo2) {
    int t = blockIdx.x * 256 + threadIdx.x;
    const float *W, *vs, *vd; unsigned short *hi, *lo; int cout, NT, tt;
    if (t < PACK1_T)            { tt = t;           W = W1; vs = v1s; vd = v1d; hi = hi1; lo = lo1; cout = HID;  NT = 17; }
    else if (t < PACK1_T + PACK2_T) { tt = t - PACK1_T; W = W2; vs = v2s; vd = v2d; hi = hi2; lo = lo2; cout = OUT_C; NT = 9; }
    else return;
    int lane = tt & 63;
    int tile = (tt >> 6) % NT;
    int ks = tt / (64 * NT);
    int m = lane & 15;
    int kbase = ks * 32 + (lane >> 4) * 8;
    #pragma unroll
    for (int j = 0; j < 8; j++) {
        float val;
        if (tile < NT - 1) val = W[(kbase + j) * cout + tile * 16 + m];
        else val = (m == 0) ? vs[kbase + j] : (m == 1) ? vd[kbase + j] : 0.f;
        unsigned short h = bf16_rne(val);
        hi[tt * 8 + j] = h;
        lo[tt * 8 + j] = bf16_rne(val - __uint_as_float((unsigned)h << 16));
    }
}

// ---------------- MFMA GEMM + attention logits: H = A@W, a_s/a_d = A@v ----------------
// 16 rows/wave (rg=1), all NT tiles per wave; block = 4 waves = 64 rows; A read ONCE.

template <int COUT>
__global__ __launch_bounds__(256) void mfma_gemm_a_kernel(
    const float* __restrict__ A, const unsigned short* __restrict__ Bhi,
    const unsigned short* __restrict__ Blo, float* __restrict__ H,
    float* __restrict__ a_s, float* __restrict__ a_d, int M) {
    const int NT = COUT / 16 + 1;   // 17 (HID) or 9 (OUT_C)
    int wave = threadIdx.x >> 6, lane = threadIdx.x & 63;
    int m = lane & 15, quad = lane >> 4;
    int row0 = blockIdx.x * 64 + wave * 16;
    f32x4 acc[NT];
    #pragma unroll
    for (int nt = 0; nt < NT; nt++) acc[nt] = (f32x4){0.f, 0.f, 0.f, 0.f};

    int r = row0 + m;
    if (r >= M) r = M - 1;          // clamp: pad rows never stored
    const float* arow = A + (size_t)r * HID;

    for (int ks = 0; ks < 8; ks++) {
        const float* ap = arow + ks * 32 + quad * 8;
        float4 v0 = *(const float4*)ap;
        float4 v1 = *(const float4*)(ap + 4);
        float av[8] = {v0.x, v0.y, v0.z, v0.w, v1.x, v1.y, v1.z, v1.w};
        bf16x8 ah, al;
        #pragma unroll
        for (int j = 0; j < 8; j++) {
            unsigned short h = bf16_rne(av[j]);
            float hf = __uint_as_float((unsigned)h << 16);
            ah[j] = (short)h;
            al[j] = (short)bf16_rne(av[j] - hf);
        }
        size_t fbase = ((size_t)ks * NT) * 512 + lane * 8;
        const unsigned short* bp = Bhi + fbase;
        const unsigned short* bq = Blo + fbase;
        #pragma unroll
        for (int nt = 0; nt < NT; nt++) {
            bf16x8 bh = *(const bf16x8*)(bp + nt * 512);
            bf16x8 bl = *(const bf16x8*)(bq + nt * 512);
            acc[nt] = __builtin_amdgcn_mfma_f32_16x16x32_bf16(ah, bh, acc[nt], 0, 0, 0);
            acc[nt] = __builtin_amdgcn_mfma_f32_16x16x32_bf16(ah, bl, acc[nt], 0, 0, 0);
            acc[nt] = __builtin_amdgcn_mfma_f32_16x16x32_bf16(al, bh, acc[nt], 0, 0, 0);
        }
    }
    // C/D layout: col = lane&15, row = quad*4 + reg  [m89-verified]
    #pragma unroll
    for (int nt = 0; nt < NT - 1; nt++)
        #pragma unroll
        for (int r2 = 0; r2 < 4; r2++) {
            int row = row0 + quad * 4 + r2;
            if (row < M) H[(size_t)row * COUT + nt * 16 + m] = acc[nt][r2];
        }
    #pragma unroll
    for (int r2 = 0; r2 < 4; r2++) {
        int row = row0 + quad * 4 + r2;
        if (row < M) {
            if (m == 0) a_s[row] = acc[NT - 1][r2];
            else if (m == 1) a_d[row] = acc[NT - 1][r2];
        }
    }
}

// ---------------- fused softmax + aggregation: one wave per dst node ----------------

template <int C, bool RELU>
__global__ __launch_bounds__(256) void fused_aggregate_kernel(
    const int* __restrict__ offsets, const int* __restrict__ src_sorted,
    const float* __restrict__ a_src, const float* __restrict__ a_dst,
    const float* __restrict__ h, const float* __restrict__ bias,
    float* __restrict__ out) {
    constexpr int CH = 8;
    int node = (int)((blockIdx.x * 256u + threadIdx.x) >> 6);
    int lane = threadIdx.x & 63;
    if (node >= N_NODES) return;
    int beg = offsets[node], end = offsets[node + 1];
    float ad = a_dst[node];
    float s = 0.f;

    if (C == 256) {
        float4 acc = make_float4(0.f, 0.f, 0.f, 0.f);
        for (int base = beg; base < end; base += CH) {
            int cnt = end - base; if (cnt > CH) cnt = CH;
            int idx[CH];
            #pragma unroll
            for (int j = 0; j < CH; j++)
                idx[j] = src_sorted[(j < cnt) ? base + j : base];
            float4 hv[CH];
            #pragma unroll
            for (int j = 0; j < CH; j++)
                hv[j] = *(const float4*)(h + (size_t)idx[j] * C + lane * 4);
            float w[CH];
            #pragma unroll
            for (int j = 0; j < CH; j++) {
                float l = a_src[idx[j]] + ad;
                if (l < 0.f) l *= NEG_SLOPE;
                w[j] = (j < cnt) ? expf(l) : 0.f;
                s += w[j];
            }
            #pragma unroll
            for (int j = 0; j < CH; j++) {
                acc.x += w[j] * hv[j].x; acc.y += w[j] * hv[j].y;
                acc.z += w[j] * hv[j].z; acc.w += w[j] * hv[j].w;
            }
        }
        float inv = 1.f / (s + 1e-16f);
        float4 bv = *(const float4*)(bias + lane * 4);
        acc.x = acc.x * inv + bv.x; acc.y = acc.y * inv + bv.y;
        acc.z = acc.z * inv + bv.z; acc.w = acc.w * inv + bv.w;
        if (RELU) {
            acc.x = fmaxf(acc.x, 0.f); acc.y = fmaxf(acc.y, 0.f);
            acc.z = fmaxf(acc.z, 0.f); acc.w = fmaxf(acc.w, 0.f);
        }
        *(float4*)(out + (size_t)node * C + lane * 4) = acc;
    } else {
        float2 acc = make_float2(0.f, 0.f);
        for (int base = beg; base < end; base += CH) {
            int cnt = end - base; if (cnt > CH) cnt = CH;
            int idx[CH];
            #pragma unroll
            for (int j = 0; j < CH; j++)
                idx[j] = src_sorted[(j < cnt) ? base + j : base];
            float2 hv[CH];
            #pragma unroll
            for (int j = 0; j < CH; j++)
                hv[j] = *(const float2*)(h + (size_t)idx[j] * C + lane * 2);
            float w[CH];
            #pragma unroll
            for (int j = 0; j < CH; j++) {
                float l = a_src[idx[j]] + ad;
                if (l < 0.f) l *= NEG_SLOPE;
                w[j] = (j < cnt) ? expf(l) : 0.f;
                s += w[j];
            }
            #pragma unroll
            for (int j = 0; j < CH; j++) {
                acc.x += w[j] * hv[j].x; acc.y += w[j] * hv[j].y;
            }
        }
        float inv = 1.f / (s + 1e-16f);
        float2 bv = *(const float2*)(bias + lane * 2);
        acc.x = acc.x * inv + bv.x; acc.y = acc.y * inv + bv.y;
        if (RELU) { acc.x = fmaxf(acc.x, 0.f); acc.y = fmaxf(acc.y, 0.f); }
        *(float2*)(out + (size_t)node * C + lane * 2) = acc;
    }
}

extern "C" void kernel_launch(void* const* d_in, const int* in_sizes, int n_in,
                              void* d_out, int out_size, void* d_ws, size_t ws_size,
                              hipStream_t stream) {
    const float* x     = (const float*)d_in[0];
    const int*   edge  = (const int*)d_in[1];
    const int*   src   = edge;
    const int*   dst   = edge + N_EDGES;
    const float* W1s   = (const float*)d_in[2];
    const float* W1d   = (const float*)d_in[3];
    const float* att1s = (const float*)d_in[4];
    const float* att1d = (const float*)d_in[5];
    const float* b1    = (const float*)d_in[6];
    const float* W2s   = (const float*)d_in[7];
    const float* W2d   = (const float*)d_in[8];
    const float* att2s = (const float*)d_in[9];
    const float* att2d = (const float*)d_in[10];
    const float* b2    = (const float*)d_in[11];
    float* out = (float*)d_out;

    // -------- workspace layout --------
    float* ws    = (float*)d_ws;
    float* h1    = ws;                                 // N*256  (reused as h2)
    float* act2  = h1 + (size_t)N_NODES * HID;         // N*256
    float* a_s   = act2 + (size_t)N_NODES * HID;       // N
    float* a_d   = a_s + N_NODES;                      // N
    float* vbuf  = a_d + N_NODES;                      // 4*256
    int* ibase      = (int*)(vbuf + 4 * HID);
    int* src_sorted = ibase;                           // E
    int* counts     = src_sorted + N_EDGES;            // N (also cursor)
    int* offsets    = counts + N_NODES;                // N+1
    int* blockSums  = offsets + N_NODES + 1;           // SCAN_NB
    unsigned short* wp1h = (unsigned short*)(((uintptr_t)(blockSums + SCAN_NB) + 15) & ~(uintptr_t)15);
    unsigned short* wp1l = wp1h + PACK1_T * 8;         // 69632 each
    unsigned short* wp2h = wp1l + PACK1_T * 8;
    unsigned short* wp2l = wp2h + PACK2_T * 8;         // 36864 each
    float* v1s = vbuf, *v1d = vbuf + HID, *v2s = vbuf + 2 * HID, *v2d = vbuf + 3 * HID;
    float* h2 = h1;

    const int edgeBlocks = (N_EDGES + 255) / 256;
    const int waveBlocksN = (N_NODES + 3) / 4;
    const int gemmBlocks = (N_NODES + 63) / 64;        // 782

    // -------- CSR build --------
    hipMemsetAsync(counts, 0, N_NODES * sizeof(int), stream);
    hist_kernel<<<edgeBlocks, 256, 0, stream>>>(dst, counts);
    block_scan_kernel<<<SCAN_NB, 256, 0, stream>>>(counts, offsets, blockSums, N_NODES);
    scan_sums_kernel<<<1, 64, 0, stream>>>(blockSums, SCAN_NB);
    add_offsets_kernel<<<SCAN_NB, 256, 0, stream>>>(offsets, blockSums, counts, N_NODES);
    scatter_kernel<<<edgeBlocks, 256, 0, stream>>>(src, dst, offsets, counts, src_sorted);

    // -------- v vectors + packed B (both layers, one kernel each) --------
    compute_v_all_kernel<<<dim3(HID, 4), 64, 0, stream>>>(
        W1s, att1s, W1d, att1d, W2s, att2s, W2d, att2d, v1s, v1d, v2s, v2d);
    pack_all_kernel<<<(PACK1_T + PACK2_T + 255) / 256, 256, 0, stream>>>(
        W1s, v1s, v1d, W2s, v2s, v2d, wp1h, wp1l, wp2h, wp2l);

    // -------- layer 1 --------
    mfma_gemm_a_kernel<HID><<<gemmBlocks, 256, 0, stream>>>(
        x, wp1h, wp1l, h1, a_s, a_d, N_NODES);
    fused_aggregate_kernel<HID, true><<<waveBlocksN, 256, 0, stream>>>(
        offsets, src_sorted, a_s, a_d, h1, b1, act2);

    // -------- layer 2 --------
    mfma_gemm_a_kernel<OUT_C><<<gemmBlocks, 256, 0, stream>>>(
        act2, wp2h, wp2l, h2, a_s, a_d, N_NODES);
    fused_aggregate_kernel<OUT_C, false><<<waveBlocksN, 256, 0, stream>>>(
        offsets, src_sorted, a_s, a_d, h2, b2, out);
}

// Round 7
// 405.762 us; speedup vs baseline: 1.1638x; 1.1638x over previous
//
#include <hip/hip_runtime.h>
#include <math.h>

#define N_NODES 50000
#define N_EDGES 800000
#define HID 256
#define OUT_C 128
#define NEG_SLOPE 0.2f
#define SCAN_NB ((N_NODES + 255) / 256)   // 196

typedef __attribute__((ext_vector_type(8))) short bf16x8;   // 8 bf16 (4 VGPRs)
typedef __attribute__((ext_vector_type(4))) float f32x4;    // MFMA C/D

__device__ inline unsigned short bf16_rne(float x) {
    unsigned u = __float_as_uint(x);
    return (unsigned short)((u + 0x7fffu + ((u >> 16) & 1u)) >> 16);
}

// ---------------- CSR build: hist (+rank), scan, atomic-free scatter ----------------

// rank[e] = arrival order within dst segment; counts[d] = degree
__global__ __launch_bounds__(256) void hist_rank_kernel(
    const int* __restrict__ dst, int* __restrict__ counts, int* __restrict__ rank) {
    int e = blockIdx.x * 256 + threadIdx.x;
    if (e < N_EDGES) rank[e] = atomicAdd(&counts[dst[e]], 1);
}

__global__ __launch_bounds__(256) void block_scan_kernel(
    const int* __restrict__ counts, int* __restrict__ excl,
    int* __restrict__ blockSums, int n) {
    __shared__ int waveSums[4];
    int i = blockIdx.x * 256 + threadIdx.x;
    int lane = threadIdx.x & 63;
    int wv = threadIdx.x >> 6;
    int c = (i < n) ? counts[i] : 0;
    int v = c;
    #pragma unroll
    for (int off = 1; off < 64; off <<= 1) {
        int t = __shfl_up(v, off);
        if (lane >= off) v += t;
    }
    if (lane == 63) waveSums[wv] = v;
    __syncthreads();
    int waveOff = 0;
    #pragma unroll
    for (int w = 0; w < 4; w++)
        if (w < wv) waveOff += waveSums[w];
    if (i < n) excl[i] = waveOff + v - c;
    if (threadIdx.x == 255) blockSums[blockIdx.x] = waveOff + v;
}

// each block computes its own prefix over blockSums (196 ints, L2-resident) inline
__global__ __launch_bounds__(256) void add_offsets_kernel(
    int* __restrict__ excl, const int* __restrict__ blockSums, int n) {
    __shared__ int lds[4];
    int tid = threadIdx.x;
    int partial = 0;
    for (int j = tid; j < (int)blockIdx.x; j += 256) partial += blockSums[j];
    #pragma unroll
    for (int off = 32; off > 0; off >>= 1) partial += __shfl_down(partial, off);
    if ((tid & 63) == 0) lds[tid >> 6] = partial;
    __syncthreads();
    int prefix = lds[0] + lds[1] + lds[2] + lds[3];
    int i = blockIdx.x * 256 + tid;
    if (i < n) excl[i] += prefix;
    if (i == 0) excl[n] = N_EDGES;
}

// atomic-free: position = offsets[dst] + rank
__global__ __launch_bounds__(256) void scatter_kernel(
    const int* __restrict__ src, const int* __restrict__ dst,
    const int* __restrict__ offsets, const int* __restrict__ rank,
    int* __restrict__ src_sorted) {
    int e = blockIdx.x * 256 + threadIdx.x;
    if (e >= N_EDGES) return;
    src_sorted[offsets[dst[e]] + rank[e]] = src[e];
}

// ---------------- v = W @ att for all 4 (layer,side) combos ----------------

__global__ __launch_bounds__(64) void compute_v_all_kernel(
    const float* __restrict__ W1s, const float* __restrict__ att1s,
    const float* __restrict__ W1d, const float* __restrict__ att1d,
    const float* __restrict__ W2s, const float* __restrict__ att2s,
    const float* __restrict__ W2d, const float* __restrict__ att2d,
    float* __restrict__ v1s, float* __restrict__ v1d,
    float* __restrict__ v2s, float* __restrict__ v2d) {
    int k = blockIdx.x;
    int lane = threadIdx.x;
    const float* W; const float* att; float* v; int cout;
    switch (blockIdx.y) {
        case 0: W = W1s; att = att1s; v = v1s; cout = HID; break;
        case 1: W = W1d; att = att1d; v = v1d; cout = HID; break;
        case 2: W = W2s; att = att2s; v = v2s; cout = OUT_C; break;
        default: W = W2d; att = att2d; v = v2d; cout = OUT_C; break;
    }
    float sum = 0.f;
    for (int j = lane; j < cout; j += 64)
        sum += W[k * cout + j] * att[j];
    #pragma unroll
    for (int off = 32; off > 0; off >>= 1)
        sum += __shfl_down(sum, off);
    if (lane == 0) v[k] = sum;
}

// ---------------- pack W (+v tile) into B-fragment layout, hi/lo bf16 ----------------
// frag index = (ks*NTL + tile)*64 + lane, 8 elems each. tile < NTL-1: W cols;
// tile == NTL-1 (a-tile): col0=v_s[k], col1=v_d[k], else 0.

#define PACK1_T (8 * 17 * 64)   // 8704
#define PACK2_T (8 * 9 * 64)    // 4608

__global__ __launch_bounds__(256) void pack_all_kernel(
    const float* __restrict__ W1, const float* __restrict__ v1s, const float* __restrict__ v1d,
    const float* __restrict__ W2, const float* __restrict__ v2s, const float* __restrict__ v2d,
    unsigned short* __restrict__ hi1, unsigned short* __restrict__ lo1,
    unsigned short* __restrict__ hi2, unsigned short* __restrict__ lo2) {
    int t = blockIdx.x * 256 + threadIdx.x;
    const float *W, *vs, *vd; unsigned short *hi, *lo; int cout, NTL, tt;
    if (t < PACK1_T)            { tt = t;           W = W1; vs = v1s; vd = v1d; hi = hi1; lo = lo1; cout = HID;  NTL = 17; }
    else if (t < PACK1_T + PACK2_T) { tt = t - PACK1_T; W = W2; vs = v2s; vd = v2d; hi = hi2; lo = lo2; cout = OUT_C; NTL = 9; }
    else return;
    int lane = tt & 63;
    int tile = (tt >> 6) % NTL;
    int ks = tt / (64 * NTL);
    int m = lane & 15;
    int kbase = ks * 32 + (lane >> 4) * 8;
    #pragma unroll
    for (int j = 0; j < 8; j++) {
        float val;
        if (tile < NTL - 1) val = W[(kbase + j) * cout + tile * 16 + m];
        else val = (m == 0) ? vs[kbase + j] : (m == 1) ? vd[kbase + j] : 0.f;
        unsigned short h = bf16_rne(val);
        hi[tt * 8 + j] = h;
        lo[tt * 8 + j] = bf16_rne(val - __uint_as_float((unsigned)h << 16));
    }
}

// ---------------- MFMA GEMM (+ logits): 32 rows/wave, 8 W-tiles (+a-tile) ----------------

template <int COUT, int NT, bool WRITE_A>
__device__ __forceinline__ void gemm_body(
    const float* __restrict__ A, const unsigned short* __restrict__ Bhi,
    const unsigned short* __restrict__ Blo, float* __restrict__ H,
    float* __restrict__ a_s, float* __restrict__ a_d, int M, int tile0) {
    const int NTL = COUT / 16 + 1;
    int wave = threadIdx.x >> 6, lane = threadIdx.x & 63;
    int m = lane & 15, quad = lane >> 4;
    int row0 = blockIdx.x * 128 + wave * 32;
    f32x4 acc[2][NT];
    #pragma unroll
    for (int rg = 0; rg < 2; rg++)
        #pragma unroll
        for (int nt = 0; nt < NT; nt++)
            acc[rg][nt] = (f32x4){0.f, 0.f, 0.f, 0.f};

    const float* arow[2];
    #pragma unroll
    for (int rg = 0; rg < 2; rg++) {
        int r = row0 + rg * 16 + m;
        if (r >= M) r = M - 1;          // clamp: pad rows never stored
        arow[rg] = A + (size_t)r * HID;
    }

    for (int ks = 0; ks < 8; ks++) {
        bf16x8 ah[2], al[2];
        #pragma unroll
        for (int rg = 0; rg < 2; rg++) {
            const float* ap = arow[rg] + ks * 32 + quad * 8;
            float4 v0 = *(const float4*)ap;
            float4 v1 = *(const float4*)(ap + 4);
            float av[8] = {v0.x, v0.y, v0.z, v0.w, v1.x, v1.y, v1.z, v1.w};
            #pragma unroll
            for (int j = 0; j < 8; j++) {
                unsigned short h = bf16_rne(av[j]);
                float hf = __uint_as_float((unsigned)h << 16);
                ah[rg][j] = (short)h;
                al[rg][j] = (short)bf16_rne(av[j] - hf);
            }
        }
        #pragma unroll
        for (int nt = 0; nt < NT; nt++) {
            int tile = (WRITE_A && nt == NT - 1) ? (COUT / 16) : (tile0 + nt);
            size_t fbase = ((size_t)(ks * NTL + tile) * 64 + lane) * 8;
            bf16x8 bh = *(const bf16x8*)(Bhi + fbase);
            bf16x8 bl = *(const bf16x8*)(Blo + fbase);
            acc[0][nt] = __builtin_amdgcn_mfma_f32_16x16x32_bf16(ah[0], bh, acc[0][nt], 0, 0, 0);
            acc[1][nt] = __builtin_amdgcn_mfma_f32_16x16x32_bf16(ah[1], bh, acc[1][nt], 0, 0, 0);
            acc[0][nt] = __builtin_amdgcn_mfma_f32_16x16x32_bf16(ah[0], bl, acc[0][nt], 0, 0, 0);
            acc[1][nt] = __builtin_amdgcn_mfma_f32_16x16x32_bf16(ah[1], bl, acc[1][nt], 0, 0, 0);
            acc[0][nt] = __builtin_amdgcn_mfma_f32_16x16x32_bf16(al[0], bh, acc[0][nt], 0, 0, 0);
            acc[1][nt] = __builtin_amdgcn_mfma_f32_16x16x32_bf16(al[1], bh, acc[1][nt], 0, 0, 0);
        }
    }
    // C/D layout: col = lane&15, row = quad*4 + reg  [m89-verified]
    const int NW = WRITE_A ? NT - 1 : NT;
    #pragma unroll
    for (int rg = 0; rg < 2; rg++)
        #pragma unroll
        for (int nt = 0; nt < NW; nt++)
            #pragma unroll
            for (int r = 0; r < 4; r++) {
                int row = row0 + rg * 16 + quad * 4 + r;
                if (row < M)
                    H[(size_t)row * COUT + (tile0 + nt) * 16 + m] = acc[rg][nt][r];
            }
    if (WRITE_A) {
        #pragma unroll
        for (int rg = 0; rg < 2; rg++)
            #pragma unroll
            for (int r = 0; r < 4; r++) {
                int row = row0 + rg * 16 + quad * 4 + r;
                if (row < M) {
                    if (m == 0) a_s[row] = acc[rg][NT - 1][r];
                    else if (m == 1) a_d[row] = acc[rg][NT - 1][r];
                }
            }
    }
}

// layer1 (COUT=256): grid.y=2 — y0: cols 0..127 + a-tile; y1: cols 128..255
// layer2 (COUT=128): grid.y=1 — cols 0..127 + a-tile
template <int COUT>
__global__ __launch_bounds__(256) void mfma_gemm_a_kernel(
    const float* __restrict__ A, const unsigned short* __restrict__ Bhi,
    const unsigned short* __restrict__ Blo, float* __restrict__ H,
    float* __restrict__ a_s, float* __restrict__ a_d, int M) {
    if (blockIdx.y == 0)
        gemm_body<COUT, 9, true>(A, Bhi, Blo, H, a_s, a_d, M, 0);
    else
        gemm_body<COUT, 8, false>(A, Bhi, Blo, H, a_s, a_d, M, 8);
}

// ---------------- fused softmax + aggregation: one wave per dst node ----------------

template <int C, bool RELU>
__global__ __launch_bounds__(256) void fused_aggregate_kernel(
    const int* __restrict__ offsets, const int* __restrict__ src_sorted,
    const float* __restrict__ a_src, const float* __restrict__ a_dst,
    const float* __restrict__ h, const float* __restrict__ bias,
    float* __restrict__ out) {
    constexpr int CH = 8;
    int node = (int)((blockIdx.x * 256u + threadIdx.x) >> 6);
    int lane = threadIdx.x & 63;
    if (node >= N_NODES) return;
    int beg = offsets[node], end = offsets[node + 1];
    float ad = a_dst[node];
    float s = 0.f;

    if (C == 256) {
        float4 acc = make_float4(0.f, 0.f, 0.f, 0.f);
        for (int base = beg; base < end; base += CH) {
            int cnt = end - base; if (cnt > CH) cnt = CH;
            int idx[CH];
            #pragma unroll
            for (int j = 0; j < CH; j++)
                idx[j] = src_sorted[(j < cnt) ? base + j : base];
            float4 hv[CH];
            #pragma unroll
            for (int j = 0; j < CH; j++)
                hv[j] = *(const float4*)(h + (size_t)idx[j] * C + lane * 4);
            float w[CH];
            #pragma unroll
            for (int j = 0; j < CH; j++) {
                float l = a_src[idx[j]] + ad;
                if (l < 0.f) l *= NEG_SLOPE;
                w[j] = (j < cnt) ? expf(l) : 0.f;
                s += w[j];
            }
            #pragma unroll
            for (int j = 0; j < CH; j++) {
                acc.x += w[j] * hv[j].x; acc.y += w[j] * hv[j].y;
                acc.z += w[j] * hv[j].z; acc.w += w[j] * hv[j].w;
            }
        }
        float inv = 1.f / (s + 1e-16f);
        float4 bv = *(const float4*)(bias + lane * 4);
        acc.x = acc.x * inv + bv.x; acc.y = acc.y * inv + bv.y;
        acc.z = acc.z * inv + bv.z; acc.w = acc.w * inv + bv.w;
        if (RELU) {
            acc.x = fmaxf(acc.x, 0.f); acc.y = fmaxf(acc.y, 0.f);
            acc.z = fmaxf(acc.z, 0.f); acc.w = fmaxf(acc.w, 0.f);
        }
        *(float4*)(out + (size_t)node * C + lane * 4) = acc;
    } else {
        float2 acc = make_float2(0.f, 0.f);
        for (int base = beg; base < end; base += CH) {
            int cnt = end - base; if (cnt > CH) cnt = CH;
            int idx[CH];
            #pragma unroll
            for (int j = 0; j < CH; j++)
                idx[j] = src_sorted[(j < cnt) ? base + j : base];
            float2 hv[CH];
            #pragma unroll
            for (int j = 0; j < CH; j++)
                hv[j] = *(const float2*)(h + (size_t)idx[j] * C + lane * 2);
            float w[CH];
            #pragma unroll
            for (int j = 0; j < CH; j++) {
                float l = a_src[idx[j]] + ad;
                if (l < 0.f) l *= NEG_SLOPE;
                w[j] = (j < cnt) ? expf(l) : 0.f;
                s += w[j];
            }
            #pragma unroll
            for (int j = 0; j < CH; j++) {
                acc.x += w[j] * hv[j].x; acc.y += w[j] * hv[j].y;
            }
        }
        float inv = 1.f / (s + 1e-16f);
        float2 bv = *(const float2*)(bias + lane * 2);
        acc.x = acc.x * inv + bv.x; acc.y = acc.y * inv + bv.y;
        if (RELU) { acc.x = fmaxf(acc.x, 0.f); acc.y = fmaxf(acc.y, 0.f); }
        *(float2*)(out + (size_t)node * C + lane * 2) = acc;
    }
}

extern "C" void kernel_launch(void* const* d_in, const int* in_sizes, int n_in,
                              void* d_out, int out_size, void* d_ws, size_t ws_size,
                              hipStream_t stream) {
    const float* x     = (const float*)d_in[0];
    const int*   edge  = (const int*)d_in[1];
    const int*   src   = edge;
    const int*   dst   = edge + N_EDGES;
    const float* W1s   = (const float*)d_in[2];
    const float* W1d   = (const float*)d_in[3];
    const float* att1s = (const float*)d_in[4];
    const float* att1d = (const float*)d_in[5];
    const float* b1    = (const float*)d_in[6];
    const float* W2s   = (const float*)d_in[7];
    const float* W2d   = (const float*)d_in[8];
    const float* att2s = (const float*)d_in[9];
    const float* att2d = (const float*)d_in[10];
    const float* b2    = (const float*)d_in[11];
    float* out = (float*)d_out;

    // -------- workspace layout --------
    float* ws    = (float*)d_ws;
    float* h1    = ws;                                 // N*256  (reused as h2)
    float* act2  = h1 + (size_t)N_NODES * HID;         // N*256
    float* a_s   = act2 + (size_t)N_NODES * HID;       // N
    float* a_d   = a_s + N_NODES;                      // N
    float* vbuf  = a_d + N_NODES;                      // 4*256
    int* ibase      = (int*)(vbuf + 4 * HID);
    int* src_sorted = ibase;                           // E
    int* rank       = src_sorted + N_EDGES;            // E
    int* counts     = rank + N_EDGES;                  // N
    int* offsets    = counts + N_NODES;                // N+1
    int* blockSums  = offsets + N_NODES + 1;           // SCAN_NB
    unsigned short* wp1h = (unsigned short*)(((uintptr_t)(blockSums + SCAN_NB) + 15) & ~(uintptr_t)15);
    unsigned short* wp1l = wp1h + PACK1_T * 8;         // 69632 each
    unsigned short* wp2h = wp1l + PACK1_T * 8;
    unsigned short* wp2l = wp2h + PACK2_T * 8;         // 36864 each
    float* v1s = vbuf, *v1d = vbuf + HID, *v2s = vbuf + 2 * HID, *v2d = vbuf + 3 * HID;
    float* h2 = h1;

    const int edgeBlocks = (N_EDGES + 255) / 256;
    const int waveBlocksN = (N_NODES + 3) / 4;
    const int gemmBlocks = (N_NODES + 127) / 128;      // 391

    // -------- CSR build (atomic only in hist; scatter is rank-addressed) --------
    hipMemsetAsync(counts, 0, N_NODES * sizeof(int), stream);
    hist_rank_kernel<<<edgeBlocks, 256, 0, stream>>>(dst, counts, rank);
    block_scan_kernel<<<SCAN_NB, 256, 0, stream>>>(counts, offsets, blockSums, N_NODES);
    add_offsets_kernel<<<SCAN_NB, 256, 0, stream>>>(offsets, blockSums, N_NODES);
    scatter_kernel<<<edgeBlocks, 256, 0, stream>>>(src, dst, offsets, rank, src_sorted);

    // -------- v vectors + packed B (both layers) --------
    compute_v_all_kernel<<<dim3(HID, 4), 64, 0, stream>>>(
        W1s, att1s, W1d, att1d, W2s, att2s, W2d, att2d, v1s, v1d, v2s, v2d);
    pack_all_kernel<<<(PACK1_T + PACK2_T + 255) / 256, 256, 0, stream>>>(
        W1s, v1s, v1d, W2s, v2s, v2d, wp1h, wp1l, wp2h, wp2l);

    // -------- layer 1 --------
    mfma_gemm_a_kernel<HID><<<dim3(gemmBlocks, 2), 256, 0, stream>>>(
        x, wp1h, wp1l, h1, a_s, a_d, N_NODES);
    fused_aggregate_kernel<HID, true><<<waveBlocksN, 256, 0, stream>>>(
        offsets, src_sorted, a_s, a_d, h1, b1, act2);

    // -------- layer 2 --------
    mfma_gemm_a_kernel<OUT_C><<<dim3(gemmBlocks, 1), 256, 0, stream>>>(
        act2, wp2h, wp2l, h2, a_s, a_d, N_NODES);
    fused_aggregate_kernel<OUT_C, false><<<waveBlocksN, 256, 0, stream>>>(
        offsets, src_sorted, a_s, a_d, h2, b2, out);
}

// Round 8
// 339.645 us; speedup vs baseline: 1.3904x; 1.1947x over previous
//
#include <hip/hip_runtime.h>
#include <math.h>

#define N_NODES 50000
#define N_EDGES 800000
#define HID 256
#define OUT_C 128
#define NEG_SLOPE 0.2f
#define SCAN_NB ((N_NODES + 255) / 256)   // 196

typedef __attribute__((ext_vector_type(8))) short bf16x8;   // 8 bf16 (4 VGPRs)
typedef __attribute__((ext_vector_type(4))) float f32x4;    // MFMA C/D
typedef _Float16 half_t;
typedef __attribute__((ext_vector_type(4))) _Float16 half4;
typedef __attribute__((ext_vector_type(2))) _Float16 half2t;

__device__ inline unsigned short bf16_rne(float x) {
    unsigned u = __float_as_uint(x);
    return (unsigned short)((u + 0x7fffu + ((u >> 16) & 1u)) >> 16);
}

// ---------------- CSR build: hist (+rank), scan, atomic-free scatter ----------------

__global__ __launch_bounds__(256) void hist_rank_kernel(
    const int* __restrict__ dst, int* __restrict__ counts, int* __restrict__ rank) {
    int e = blockIdx.x * 256 + threadIdx.x;
    if (e < N_EDGES) rank[e] = atomicAdd(&counts[dst[e]], 1);
}

__global__ __launch_bounds__(256) void block_scan_kernel(
    const int* __restrict__ counts, int* __restrict__ excl,
    int* __restrict__ blockSums, int n) {
    __shared__ int waveSums[4];
    int i = blockIdx.x * 256 + threadIdx.x;
    int lane = threadIdx.x & 63;
    int wv = threadIdx.x >> 6;
    int c = (i < n) ? counts[i] : 0;
    int v = c;
    #pragma unroll
    for (int off = 1; off < 64; off <<= 1) {
        int t = __shfl_up(v, off);
        if (lane >= off) v += t;
    }
    if (lane == 63) waveSums[wv] = v;
    __syncthreads();
    int waveOff = 0;
    #pragma unroll
    for (int w = 0; w < 4; w++)
        if (w < wv) waveOff += waveSums[w];
    if (i < n) excl[i] = waveOff + v - c;
    if (threadIdx.x == 255) blockSums[blockIdx.x] = waveOff + v;
}

__global__ __launch_bounds__(256) void add_offsets_kernel(
    int* __restrict__ excl, const int* __restrict__ blockSums, int n) {
    __shared__ int lds[4];
    int tid = threadIdx.x;
    int partial = 0;
    for (int j = tid; j < (int)blockIdx.x; j += 256) partial += blockSums[j];
    #pragma unroll
    for (int off = 32; off > 0; off >>= 1) partial += __shfl_down(partial, off);
    if ((tid & 63) == 0) lds[tid >> 6] = partial;
    __syncthreads();
    int prefix = lds[0] + lds[1] + lds[2] + lds[3];
    int i = blockIdx.x * 256 + tid;
    if (i < n) excl[i] += prefix;
    if (i == 0) excl[n] = N_EDGES;
}

__global__ __launch_bounds__(256) void scatter_kernel(
    const int* __restrict__ src, const int* __restrict__ dst,
    const int* __restrict__ offsets, const int* __restrict__ rank,
    int* __restrict__ src_sorted) {
    int e = blockIdx.x * 256 + threadIdx.x;
    if (e >= N_EDGES) return;
    src_sorted[offsets[dst[e]] + rank[e]] = src[e];
}

// ---------------- v = W @ att for all 4 (layer,side) combos ----------------

__global__ __launch_bounds__(64) void compute_v_all_kernel(
    const float* __restrict__ W1s, const float* __restrict__ att1s,
    const float* __restrict__ W1d, const float* __restrict__ att1d,
    const float* __restrict__ W2s, const float* __restrict__ att2s,
    const float* __restrict__ W2d, const float* __restrict__ att2d,
    float* __restrict__ v1s, float* __restrict__ v1d,
    float* __restrict__ v2s, float* __restrict__ v2d) {
    int k = blockIdx.x;
    int lane = threadIdx.x;
    const float* W; const float* att; float* v; int cout;
    switch (blockIdx.y) {
        case 0: W = W1s; att = att1s; v = v1s; cout = HID; break;
        case 1: W = W1d; att = att1d; v = v1d; cout = HID; break;
        case 2: W = W2s; att = att2s; v = v2s; cout = OUT_C; break;
        default: W = W2d; att = att2d; v = v2d; cout = OUT_C; break;
    }
    float sum = 0.f;
    for (int j = lane; j < cout; j += 64)
        sum += W[k * cout + j] * att[j];
    #pragma unroll
    for (int off = 32; off > 0; off >>= 1)
        sum += __shfl_down(sum, off);
    if (lane == 0) v[k] = sum;
}

// ---------------- pack W (+v tile) into B-fragment layout, hi/lo bf16 ----------------

#define PACK1_T (8 * 17 * 64)   // 8704
#define PACK2_T (8 * 9 * 64)    // 4608

__global__ __launch_bounds__(256) void pack_all_kernel(
    const float* __restrict__ W1, const float* __restrict__ v1s, const float* __restrict__ v1d,
    const float* __restrict__ W2, const float* __restrict__ v2s, const float* __restrict__ v2d,
    unsigned short* __restrict__ hi1, unsigned short* __restrict__ lo1,
    unsigned short* __restrict__ hi2, unsigned short* __restrict__ lo2) {
    int t = blockIdx.x * 256 + threadIdx.x;
    const float *W, *vs, *vd; unsigned short *hi, *lo; int cout, NTL, tt;
    if (t < PACK1_T)            { tt = t;           W = W1; vs = v1s; vd = v1d; hi = hi1; lo = lo1; cout = HID;  NTL = 17; }
    else if (t < PACK1_T + PACK2_T) { tt = t - PACK1_T; W = W2; vs = v2s; vd = v2d; hi = hi2; lo = lo2; cout = OUT_C; NTL = 9; }
    else return;
    int lane = tt & 63;
    int tile = (tt >> 6) % NTL;
    int ks = tt / (64 * NTL);
    int m = lane & 15;
    int kbase = ks * 32 + (lane >> 4) * 8;
    #pragma unroll
    for (int j = 0; j < 8; j++) {
        float val;
        if (tile < NTL - 1) val = W[(kbase + j) * cout + tile * 16 + m];
        else val = (m == 0) ? vs[kbase + j] : (m == 1) ? vd[kbase + j] : 0.f;
        unsigned short h = bf16_rne(val);
        hi[tt * 8 + j] = h;
        lo[tt * 8 + j] = bf16_rne(val - __uint_as_float((unsigned)h << 16));
    }
}

// ---------------- MFMA GEMM (+ logits): 32 rows/wave, 8 W-tiles (+a-tile) ----------------
// H written as fp16 (halves aggregate gather traffic; RNE convert, err ~2^-11)

template <int COUT, int NT, bool WRITE_A>
__device__ __forceinline__ void gemm_body(
    const float* __restrict__ A, const unsigned short* __restrict__ Bhi,
    const unsigned short* __restrict__ Blo, half_t* __restrict__ H,
    float* __restrict__ a_s, float* __restrict__ a_d, int M, int tile0) {
    const int NTL = COUT / 16 + 1;
    int wave = threadIdx.x >> 6, lane = threadIdx.x & 63;
    int m = lane & 15, quad = lane >> 4;
    int row0 = blockIdx.x * 128 + wave * 32;
    f32x4 acc[2][NT];
    #pragma unroll
    for (int rg = 0; rg < 2; rg++)
        #pragma unroll
        for (int nt = 0; nt < NT; nt++)
            acc[rg][nt] = (f32x4){0.f, 0.f, 0.f, 0.f};

    const float* arow[2];
    #pragma unroll
    for (int rg = 0; rg < 2; rg++) {
        int r = row0 + rg * 16 + m;
        if (r >= M) r = M - 1;          // clamp: pad rows never stored
        arow[rg] = A + (size_t)r * HID;
    }

    for (int ks = 0; ks < 8; ks++) {
        bf16x8 ah[2], al[2];
        #pragma unroll
        for (int rg = 0; rg < 2; rg++) {
            const float* ap = arow[rg] + ks * 32 + quad * 8;
            float4 v0 = *(const float4*)ap;
            float4 v1 = *(const float4*)(ap + 4);
            float av[8] = {v0.x, v0.y, v0.z, v0.w, v1.x, v1.y, v1.z, v1.w};
            #pragma unroll
            for (int j = 0; j < 8; j++) {
                unsigned short h = bf16_rne(av[j]);
                float hf = __uint_as_float((unsigned)h << 16);
                ah[rg][j] = (short)h;
                al[rg][j] = (short)bf16_rne(av[j] - hf);
            }
        }
        #pragma unroll
        for (int nt = 0; nt < NT; nt++) {
            int tile = (WRITE_A && nt == NT - 1) ? (COUT / 16) : (tile0 + nt);
            size_t fbase = ((size_t)(ks * NTL + tile) * 64 + lane) * 8;
            bf16x8 bh = *(const bf16x8*)(Bhi + fbase);
            bf16x8 bl = *(const bf16x8*)(Blo + fbase);
            acc[0][nt] = __builtin_amdgcn_mfma_f32_16x16x32_bf16(ah[0], bh, acc[0][nt], 0, 0, 0);
            acc[1][nt] = __builtin_amdgcn_mfma_f32_16x16x32_bf16(ah[1], bh, acc[1][nt], 0, 0, 0);
            acc[0][nt] = __builtin_amdgcn_mfma_f32_16x16x32_bf16(ah[0], bl, acc[0][nt], 0, 0, 0);
            acc[1][nt] = __builtin_amdgcn_mfma_f32_16x16x32_bf16(ah[1], bl, acc[1][nt], 0, 0, 0);
            acc[0][nt] = __builtin_amdgcn_mfma_f32_16x16x32_bf16(al[0], bh, acc[0][nt], 0, 0, 0);
            acc[1][nt] = __builtin_amdgcn_mfma_f32_16x16x32_bf16(al[1], bh, acc[1][nt], 0, 0, 0);
        }
    }
    // C/D layout: col = lane&15, row = quad*4 + reg  [m89-verified]
    const int NW = WRITE_A ? NT - 1 : NT;
    #pragma unroll
    for (int rg = 0; rg < 2; rg++)
        #pragma unroll
        for (int nt = 0; nt < NW; nt++)
            #pragma unroll
            for (int r = 0; r < 4; r++) {
                int row = row0 + rg * 16 + quad * 4 + r;
                if (row < M)
                    H[(size_t)row * COUT + (tile0 + nt) * 16 + m] = (half_t)acc[rg][nt][r];
            }
    if (WRITE_A) {
        #pragma unroll
        for (int rg = 0; rg < 2; rg++)
            #pragma unroll
            for (int r = 0; r < 4; r++) {
                int row = row0 + rg * 16 + quad * 4 + r;
                if (row < M) {
                    if (m == 0) a_s[row] = acc[rg][NT - 1][r];
                    else if (m == 1) a_d[row] = acc[rg][NT - 1][r];
                }
            }
    }
}

template <int COUT>
__global__ __launch_bounds__(256) void mfma_gemm_a_kernel(
    const float* __restrict__ A, const unsigned short* __restrict__ Bhi,
    const unsigned short* __restrict__ Blo, half_t* __restrict__ H,
    float* __restrict__ a_s, float* __restrict__ a_d, int M) {
    if (blockIdx.y == 0)
        gemm_body<COUT, 9, true>(A, Bhi, Blo, H, a_s, a_d, M, 0);
    else
        gemm_body<COUT, 8, false>(A, Bhi, Blo, H, a_s, a_d, M, 8);
}

// ---------------- fused softmax + aggregation: one wave per dst node ----------------
// h rows are fp16 (512B / 256B per row) — gather traffic halved vs fp32

template <int C, bool RELU>
__global__ __launch_bounds__(256) void fused_aggregate_kernel(
    const int* __restrict__ offsets, const int* __restrict__ src_sorted,
    const float* __restrict__ a_src, const float* __restrict__ a_dst,
    const half_t* __restrict__ h, const float* __restrict__ bias,
    float* __restrict__ out) {
    constexpr int CH = 8;
    int node = (int)((blockIdx.x * 256u + threadIdx.x) >> 6);
    int lane = threadIdx.x & 63;
    if (node >= N_NODES) return;
    int beg = offsets[node], end = offsets[node + 1];
    float ad = a_dst[node];
    float s = 0.f;

    if (C == 256) {
        float4 acc = make_float4(0.f, 0.f, 0.f, 0.f);
        for (int base = beg; base < end; base += CH) {
            int cnt = end - base; if (cnt > CH) cnt = CH;
            int idx[CH];
            #pragma unroll
            for (int j = 0; j < CH; j++)
                idx[j] = src_sorted[(j < cnt) ? base + j : base];
            half4 hv[CH];
            #pragma unroll
            for (int j = 0; j < CH; j++)   // 8 independent 512B gathers in flight
                hv[j] = *(const half4*)(h + (size_t)idx[j] * C + lane * 4);
            float w[CH];
            #pragma unroll
            for (int j = 0; j < CH; j++) {
                float l = a_src[idx[j]] + ad;
                if (l < 0.f) l *= NEG_SLOPE;
                w[j] = (j < cnt) ? expf(l) : 0.f;
                s += w[j];
            }
            #pragma unroll
            for (int j = 0; j < CH; j++) {
                acc.x += w[j] * (float)hv[j][0]; acc.y += w[j] * (float)hv[j][1];
                acc.z += w[j] * (float)hv[j][2]; acc.w += w[j] * (float)hv[j][3];
            }
        }
        float inv = 1.f / (s + 1e-16f);
        float4 bv = *(const float4*)(bias + lane * 4);
        acc.x = acc.x * inv + bv.x; acc.y = acc.y * inv + bv.y;
        acc.z = acc.z * inv + bv.z; acc.w = acc.w * inv + bv.w;
        if (RELU) {
            acc.x = fmaxf(acc.x, 0.f); acc.y = fmaxf(acc.y, 0.f);
            acc.z = fmaxf(acc.z, 0.f); acc.w = fmaxf(acc.w, 0.f);
        }
        *(float4*)(out + (size_t)node * C + lane * 4) = acc;
    } else {
        float2 acc = make_float2(0.f, 0.f);
        for (int base = beg; base < end; base += CH) {
            int cnt = end - base; if (cnt > CH) cnt = CH;
            int idx[CH];
            #pragma unroll
            for (int j = 0; j < CH; j++)
                idx[j] = src_sorted[(j < cnt) ? base + j : base];
            half2t hv[CH];
            #pragma unroll
            for (int j = 0; j < CH; j++)
                hv[j] = *(const half2t*)(h + (size_t)idx[j] * C + lane * 2);
            float w[CH];
            #pragma unroll
            for (int j = 0; j < CH; j++) {
                float l = a_src[idx[j]] + ad;
                if (l < 0.f) l *= NEG_SLOPE;
                w[j] = (j < cnt) ? expf(l) : 0.f;
                s += w[j];
            }
            #pragma unroll
            for (int j = 0; j < CH; j++) {
                acc.x += w[j] * (float)hv[j][0]; acc.y += w[j] * (float)hv[j][1];
            }
        }
        float inv = 1.f / (s + 1e-16f);
        float2 bv = *(const float2*)(bias + lane * 2);
        acc.x = acc.x * inv + bv.x; acc.y = acc.y * inv + bv.y;
        if (RELU) { acc.x = fmaxf(acc.x, 0.f); acc.y = fmaxf(acc.y, 0.f); }
        *(float2*)(out + (size_t)node * C + lane * 2) = acc;
    }
}

extern "C" void kernel_launch(void* const* d_in, const int* in_sizes, int n_in,
                              void* d_out, int out_size, void* d_ws, size_t ws_size,
                              hipStream_t stream) {
    const float* x     = (const float*)d_in[0];
    const int*   edge  = (const int*)d_in[1];
    const int*   src   = edge;
    const int*   dst   = edge + N_EDGES;
    const float* W1s   = (const float*)d_in[2];
    const float* W1d   = (const float*)d_in[3];
    const float* att1s = (const float*)d_in[4];
    const float* att1d = (const float*)d_in[5];
    const float* b1    = (const float*)d_in[6];
    const float* W2s   = (const float*)d_in[7];
    const float* W2d   = (const float*)d_in[8];
    const float* att2s = (const float*)d_in[9];
    const float* att2d = (const float*)d_in[10];
    const float* b2    = (const float*)d_in[11];
    float* out = (float*)d_out;

    // -------- workspace layout --------
    float* ws    = (float*)d_ws;
    half_t* h1   = (half_t*)ws;                        // N*256 halves (region sized as N*256 floats)
    float* act2  = ws + (size_t)N_NODES * HID;         // N*256 fp32
    float* a_s   = act2 + (size_t)N_NODES * HID;       // N
    float* a_d   = a_s + N_NODES;                      // N
    float* vbuf  = a_d + N_NODES;                      // 4*256
    int* ibase      = (int*)(vbuf + 4 * HID);
    int* src_sorted = ibase;                           // E
    int* rank       = src_sorted + N_EDGES;            // E
    int* counts     = rank + N_EDGES;                  // N
    int* offsets    = counts + N_NODES;                // N+1
    int* blockSums  = offsets + N_NODES + 1;           // SCAN_NB
    unsigned short* wp1h = (unsigned short*)(((uintptr_t)(blockSums + SCAN_NB) + 15) & ~(uintptr_t)15);
    unsigned short* wp1l = wp1h + PACK1_T * 8;
    unsigned short* wp2h = wp1l + PACK1_T * 8;
    unsigned short* wp2l = wp2h + PACK2_T * 8;
    float* v1s = vbuf, *v1d = vbuf + HID, *v2s = vbuf + 2 * HID, *v2d = vbuf + 3 * HID;
    half_t* h2 = h1;

    const int edgeBlocks = (N_EDGES + 255) / 256;
    const int waveBlocksN = (N_NODES + 3) / 4;
    const int gemmBlocks = (N_NODES + 127) / 128;      // 391

    // -------- CSR build (atomic only in hist; scatter is rank-addressed) --------
    hipMemsetAsync(counts, 0, N_NODES * sizeof(int), stream);
    hist_rank_kernel<<<edgeBlocks, 256, 0, stream>>>(dst, counts, rank);
    block_scan_kernel<<<SCAN_NB, 256, 0, stream>>>(counts, offsets, blockSums, N_NODES);
    add_offsets_kernel<<<SCAN_NB, 256, 0, stream>>>(offsets, blockSums, N_NODES);
    scatter_kernel<<<edgeBlocks, 256, 0, stream>>>(src, dst, offsets, rank, src_sorted);

    // -------- v vectors + packed B (both layers) --------
    compute_v_all_kernel<<<dim3(HID, 4), 64, 0, stream>>>(
        W1s, att1s, W1d, att1d, W2s, att2s, W2d, att2d, v1s, v1d, v2s, v2d);
    pack_all_kernel<<<(PACK1_T + PACK2_T + 255) / 256, 256, 0, stream>>>(
        W1s, v1s, v1d, W2s, v2s, v2d, wp1h, wp1l, wp2h, wp2l);

    // -------- layer 1 --------
    mfma_gemm_a_kernel<HID><<<dim3(gemmBlocks, 2), 256, 0, stream>>>(
        x, wp1h, wp1l, h1, a_s, a_d, N_NODES);
    fused_aggregate_kernel<HID, true><<<waveBlocksN, 256, 0, stream>>>(
        offsets, src_sorted, a_s, a_d, h1, b1, act2);

    // -------- layer 2 --------
    mfma_gemm_a_kernel<OUT_C><<<dim3(gemmBlocks, 1), 256, 0, stream>>>(
        act2, wp2h, wp2l, h2, a_s, a_d, N_NODES);
    fused_aggregate_kernel<OUT_C, false><<<waveBlocksN, 256, 0, stream>>>(
        offsets, src_sorted, a_s, a_d, h2, b2, out);
}